// Round 13
// baseline (48.241 us; speedup 1.0000x reference)
//
#include <hip/hip_runtime.h>

#define NTHR 512
#define NROW 5000
#define NB1 2503
#define NB2 1255
#define NB3 631
#define NB4 319

// db4 filters (exact values from reference)
__device__ __constant__ float DEC_LO[8] = {
    -0.010597401784997278f, 0.032883011666982945f, 0.030841381835986965f,
    -0.18703481171888114f, -0.02798376941698385f, 0.6308807679295904f,
    0.7148465705525415f, 0.23037781330885523f};
__device__ __constant__ float DEC_HI[8] = {
    -0.23037781330885523f, 0.7148465705525415f, -0.6308807679295904f,
    -0.02798376941698385f, 0.18703481171888114f, 0.030841381835986965f,
    -0.032883011666982945f, -0.010597401784997278f};
__device__ __constant__ float REC_LO[8] = {
    0.23037781330885523f, 0.7148465705525415f, 0.6308807679295904f,
    -0.02798376941698385f, -0.18703481171888114f, 0.030841381835986965f,
    0.032883011666982945f, -0.010597401784997278f};
__device__ __constant__ float REC_HI[8] = {
    -0.010597401784997278f, -0.032883011666982945f, 0.030841381835986965f,
    0.18703481171888114f, -0.02798376941698385f, -0.6308807679295904f,
    0.7148465705525415f, -0.23037781330885523f};

// two adjacent dwt outputs (i0, i0+1) from v[0..9] (taps p = 2*i0 + j)
__device__ __forceinline__ void dwt_accum2(const float v[10], float& sa0, float& sd0,
                                           float& sa1, float& sd1) {
  sa0 = sd0 = sa1 = sd1 = 0.f;
#pragma unroll
  for (int j = 0; j < 8; ++j) {
    const float lo = DEC_LO[7 - j], hi = DEC_HI[7 - j];
    sa0 = fmaf(lo, v[j], sa0);
    sd0 = fmaf(hi, v[j], sd0);
    sa1 = fmaf(lo, v[j + 2], sa1);
    sd1 = fmaf(hi, v[j + 2], sd1);
  }
}

// level-1 DWT reading x from GLOBAL, 2 outputs/thread
__device__ __forceinline__ void dwt_glob(const float* __restrict__ x, int n, int n_out,
                                         float* __restrict__ oa, float* __restrict__ od,
                                         int tid) {
  const int npair = (n_out + 1) / 2;
  for (int t = tid; t < npair; t += NTHR) {
    const int i0 = 2 * t;
    float v[10];
    if (i0 >= 3 && 2 * i0 + 4 <= n) {
      // taps x[2i0-6 .. 2i0+3], interior; 2i0-6 even -> 8B aligned
      const float2* s2 = reinterpret_cast<const float2*>(x + 2 * i0 - 6);
#pragma unroll
      for (int j = 0; j < 5; ++j) {
        const float2 p = s2[j];
        v[2 * j] = p.x;
        v[2 * j + 1] = p.y;
      }
    } else {
#pragma unroll
      for (int j = 0; j < 10; ++j) {
        const int p = 2 * i0 + j;
        const int q = (p < 6) ? (5 - p) : ((p < n + 6) ? (p - 6) : (2 * n + 5 - p));
        v[j] = x[q];
      }
    }
    float sa0, sd0, sa1, sd1;
    dwt_accum2(v, sa0, sd0, sa1, sd1);
    if (i0 + 1 < n_out) {
      *reinterpret_cast<float2*>(oa + i0) = make_float2(sa0, sa1);
      *reinterpret_cast<float2*>(od + i0) = make_float2(sd0, sd1);
    } else {
      oa[i0] = sa0;
      od[i0] = sd0;
    }
  }
}

// DWT from LDS, 2 outputs/thread
__device__ __forceinline__ void dwt_step(const float* __restrict__ src, int n, int n_out,
                                         float* __restrict__ oa, float* __restrict__ od,
                                         int tid) {
  const int npair = (n_out + 1) / 2;
  for (int t = tid; t < npair; t += NTHR) {
    const int i0 = 2 * t;
    float v[10];
    if (i0 >= 3 && 2 * i0 + 4 <= n) {
      const float2* s2 = reinterpret_cast<const float2*>(src + 2 * i0 - 6);
#pragma unroll
      for (int j = 0; j < 5; ++j) {
        const float2 p = s2[j];
        v[2 * j] = p.x;
        v[2 * j + 1] = p.y;
      }
    } else {
#pragma unroll
      for (int j = 0; j < 10; ++j) {
        const int p = 2 * i0 + j;
        const int q = (p < 6) ? (5 - p) : ((p < n + 6) ? (p - 6) : (2 * n + 5 - p));
        v[j] = src[q];
      }
    }
    float sa0, sd0, sa1, sd1;
    dwt_accum2(v, sa0, sd0, sa1, sd1);
    if (i0 + 1 < n_out) {
      *reinterpret_cast<float2*>(oa + i0) = make_float2(sa0, sa1);
      *reinterpret_cast<float2*>(od + i0) = make_float2(sd0, sd1);
    } else {
      oa[i0] = sa0;
      od[i0] = sd0;
    }
  }
}

// idwt pair: loads c[i0..i0+4], produces out[2i0..2i0+3] as float4.
// i count (n-3) is even for every stage here -> no tails.
template <bool CA, bool CD>
__device__ __forceinline__ void idwt_pair(const float* __restrict__ ca,
                                          const float* __restrict__ cd, int i0,
                                          float4& r) {
  float a[5], d[5];
  if (CA) {
    const float2 u0 = *reinterpret_cast<const float2*>(ca + i0);
    const float2 u1 = *reinterpret_cast<const float2*>(ca + i0 + 2);
    a[0] = u0.x; a[1] = u0.y; a[2] = u1.x; a[3] = u1.y; a[4] = ca[i0 + 4];
  }
  if (CD) {
    const float2 w0 = *reinterpret_cast<const float2*>(cd + i0);
    const float2 w1 = *reinterpret_cast<const float2*>(cd + i0 + 2);
    d[0] = w0.x; d[1] = w0.y; d[2] = w1.x; d[3] = w1.y; d[4] = cd[i0 + 4];
  }
  float e0 = 0.f, o0 = 0.f, e1 = 0.f, o1 = 0.f;
#pragma unroll
  for (int s = 0; s < 4; ++s) {
    const float rl0 = REC_LO[2 * s], rl1 = REC_LO[2 * s + 1];
    const float rh0 = REC_HI[2 * s], rh1 = REC_HI[2 * s + 1];
    if (CA) {
      e0 = fmaf(rl0, a[3 - s], e0);
      o0 = fmaf(rl1, a[3 - s], o0);
      e1 = fmaf(rl0, a[4 - s], e1);
      o1 = fmaf(rl1, a[4 - s], o1);
    }
    if (CD) {
      e0 = fmaf(rh0, d[3 - s], e0);
      o0 = fmaf(rh1, d[3 - s], o0);
      e1 = fmaf(rh0, d[4 - s], e1);
      o1 = fmaf(rh1, d[4 - s], o1);
    }
  }
  r = make_float4(e0, o0, e1, o1);
}

template <bool CA, bool CD>
__device__ __forceinline__ void idwt_any(const float* __restrict__ ca,
                                         const float* __restrict__ cd, int n,
                                         float* __restrict__ out, int tid) {
  const int npair = (n - 3) / 2;
  float4* out4 = reinterpret_cast<float4*>(out);
  for (int t = tid; t < npair; t += NTHR) {
    float4 r;
    idwt_pair<CA, CD>(ca, cd, 2 * t, r);
    out4[t] = r;
  }
}

__global__ __launch_bounds__(NTHR, 8) void wavelet_kernel(
    const float* __restrict__ x, float* __restrict__ out_physio,
    float* __restrict__ out_identity) {
  // LDS: 10,024 floats = 40,096 B <= 40,960 B -> 4 blocks/CU (wave cap 32/CU)
  // A: a1 -> {a3@0, d3@+632, a4@+1264, d4@+1584} -> r3@0 -> r1
  // B: d1 (live until identity write);  C: a2 -> r2;  D: d2;  E: s1
  __shared__ __align__(16) float A[2504];
  __shared__ __align__(16) float B[2504];
  __shared__ __align__(16) float E[2504];
  __shared__ __align__(16) float C[1256];
  __shared__ __align__(16) float D[1256];

  float* const a3 = A;            // 631 @ A[0..630]
  float* const d3 = A + 632;      // 631 @ A[632..1262]
  float* const a4 = A + 1264;     // 319
  float* const d4 = A + 1584;     // 319 (ends 1902 < 2504)

  const int b = blockIdx.x;
  const int tid = threadIdx.x;
  const float* xrow = x + (size_t)b * NROW;

  // S1: level-1 dwt straight from global (x row is L1/L2-resident)
  dwt_glob(xrow, NROW, NB1, A, B, tid);        // a1 -> A, d1 -> B
  __syncthreads();
  // S2
  dwt_step(A, NB1, NB2, C, D, tid);            // a2 -> C, d2 -> D
  __syncthreads();
  // S3
  dwt_step(C, NB2, NB3, a3, d3, tid);          // a1 dead: a3/d3 into A
  __syncthreads();
  // S4: dwt4 (160 pairs) packed with s1 = idwt(0,d2) (626 pairs)
  dwt_step(a3, NB3, NB4, a4, d4, tid);         // reads A[0..630], writes A[1264..]
  idwt_any<false, true>(nullptr, D, NB2, E, tid);  // s1 -> E (reads D from S2)
  __syncthreads();
  // S5: r3 (158 pairs) packed with the identity WRITE (1250 pairs) — spreads the
  // global-store burst across the kernel instead of serializing it at the end.
  idwt_any<true, true>(a4, d4, NB4, A, tid);   // r3 -> A[0..631] (a3 dead)
  idwt_any<true, true>(E, B, NB1, out_identity + (size_t)b * NROW, tid);
  __syncthreads();
  // S6
  idwt_any<true, true>(A, d3, NB3, C, tid);    // r2 -> C (a2 dead)
  __syncthreads();
  // S7
  idwt_any<true, false>(C, nullptr, NB2, A, tid);  // r1 -> A[0..2503]
  __syncthreads();
  // S8: physio write only
  idwt_any<true, false>(A, nullptr, NB1, out_physio + (size_t)b * NROW, tid);
}

extern "C" void kernel_launch(void* const* d_in, const int* in_sizes, int n_in,
                              void* d_out, int out_size, void* d_ws, size_t ws_size,
                              hipStream_t stream) {
  const float* x = (const float*)d_in[0];
  float* out = (float*)d_out;
  const int B = in_sizes[0] / NROW;  // 4096
  wavelet_kernel<<<dim3(B), dim3(NTHR), 0, stream>>>(x, out, out + (size_t)B * NROW);
}

// Round 14
// 46.946 us; speedup vs baseline: 1.0276x; 1.0276x over previous
//
#include <hip/hip_runtime.h>

#define NTHR 512
#define NROW 5000
#define NB1 2503
#define NB2 1255
#define NB3 631
#define NB4 319

// db4 filters (exact values from reference)
__device__ __constant__ float DEC_LO[8] = {
    -0.010597401784997278f, 0.032883011666982945f, 0.030841381835986965f,
    -0.18703481171888114f, -0.02798376941698385f, 0.6308807679295904f,
    0.7148465705525415f, 0.23037781330885523f};
__device__ __constant__ float DEC_HI[8] = {
    -0.23037781330885523f, 0.7148465705525415f, -0.6308807679295904f,
    -0.02798376941698385f, 0.18703481171888114f, 0.030841381835986965f,
    -0.032883011666982945f, -0.010597401784997278f};
__device__ __constant__ float REC_LO[8] = {
    0.23037781330885523f, 0.7148465705525415f, 0.6308807679295904f,
    -0.02798376941698385f, -0.18703481171888114f, 0.030841381835986965f,
    0.032883011666982945f, -0.010597401784997278f};
__device__ __constant__ float REC_HI[8] = {
    -0.010597401784997278f, -0.032883011666982945f, 0.030841381835986965f,
    0.18703481171888114f, -0.02798376941698385f, -0.6308807679295904f,
    0.7148465705525415f, -0.23037781330885523f};

// two adjacent dwt outputs (i0, i0+1) from v[0..9] (taps p = 2*i0 + j)
__device__ __forceinline__ void dwt_accum2(const float v[10], float& sa0, float& sd0,
                                           float& sa1, float& sd1) {
  sa0 = sd0 = sa1 = sd1 = 0.f;
#pragma unroll
  for (int j = 0; j < 8; ++j) {
    const float lo = DEC_LO[7 - j], hi = DEC_HI[7 - j];
    sa0 = fmaf(lo, v[j], sa0);
    sd0 = fmaf(hi, v[j], sd0);
    sa1 = fmaf(lo, v[j + 2], sa1);
    sd1 = fmaf(hi, v[j + 2], sd1);
  }
}

// level-1 DWT reading x from GLOBAL, 2 outputs/thread
__device__ __forceinline__ void dwt_glob(const float* __restrict__ x, int n, int n_out,
                                         float* __restrict__ oa, float* __restrict__ od,
                                         int tid) {
  const int npair = (n_out + 1) / 2;
  for (int t = tid; t < npair; t += NTHR) {
    const int i0 = 2 * t;
    float v[10];
    if (i0 >= 3 && 2 * i0 + 4 <= n) {
      // taps x[2i0-6 .. 2i0+3], interior; 2i0-6 even -> 8B aligned
      const float2* s2 = reinterpret_cast<const float2*>(x + 2 * i0 - 6);
#pragma unroll
      for (int j = 0; j < 5; ++j) {
        const float2 p = s2[j];
        v[2 * j] = p.x;
        v[2 * j + 1] = p.y;
      }
    } else {
#pragma unroll
      for (int j = 0; j < 10; ++j) {
        const int p = 2 * i0 + j;
        const int q = (p < 6) ? (5 - p) : ((p < n + 6) ? (p - 6) : (2 * n + 5 - p));
        v[j] = x[q];
      }
    }
    float sa0, sd0, sa1, sd1;
    dwt_accum2(v, sa0, sd0, sa1, sd1);
    if (i0 + 1 < n_out) {
      *reinterpret_cast<float2*>(oa + i0) = make_float2(sa0, sa1);
      *reinterpret_cast<float2*>(od + i0) = make_float2(sd0, sd1);
    } else {
      oa[i0] = sa0;
      od[i0] = sd0;
    }
  }
}

// DWT from LDS, 2 outputs/thread
__device__ __forceinline__ void dwt_step(const float* __restrict__ src, int n, int n_out,
                                         float* __restrict__ oa, float* __restrict__ od,
                                         int tid) {
  const int npair = (n_out + 1) / 2;
  for (int t = tid; t < npair; t += NTHR) {
    const int i0 = 2 * t;
    float v[10];
    if (i0 >= 3 && 2 * i0 + 4 <= n) {
      const float2* s2 = reinterpret_cast<const float2*>(src + 2 * i0 - 6);
#pragma unroll
      for (int j = 0; j < 5; ++j) {
        const float2 p = s2[j];
        v[2 * j] = p.x;
        v[2 * j + 1] = p.y;
      }
    } else {
#pragma unroll
      for (int j = 0; j < 10; ++j) {
        const int p = 2 * i0 + j;
        const int q = (p < 6) ? (5 - p) : ((p < n + 6) ? (p - 6) : (2 * n + 5 - p));
        v[j] = src[q];
      }
    }
    float sa0, sd0, sa1, sd1;
    dwt_accum2(v, sa0, sd0, sa1, sd1);
    if (i0 + 1 < n_out) {
      *reinterpret_cast<float2*>(oa + i0) = make_float2(sa0, sa1);
      *reinterpret_cast<float2*>(od + i0) = make_float2(sd0, sd1);
    } else {
      oa[i0] = sa0;
      od[i0] = sd0;
    }
  }
}

// idwt pair: loads c[i0..i0+4], produces out[2i0..2i0+3] as float4.
// i count (n-3) is even for every stage here -> no tails.
template <bool CA, bool CD>
__device__ __forceinline__ void idwt_pair(const float* __restrict__ ca,
                                          const float* __restrict__ cd, int i0,
                                          float4& r) {
  float a[5], d[5];
  if (CA) {
    const float2 u0 = *reinterpret_cast<const float2*>(ca + i0);
    const float2 u1 = *reinterpret_cast<const float2*>(ca + i0 + 2);
    a[0] = u0.x; a[1] = u0.y; a[2] = u1.x; a[3] = u1.y; a[4] = ca[i0 + 4];
  }
  if (CD) {
    const float2 w0 = *reinterpret_cast<const float2*>(cd + i0);
    const float2 w1 = *reinterpret_cast<const float2*>(cd + i0 + 2);
    d[0] = w0.x; d[1] = w0.y; d[2] = w1.x; d[3] = w1.y; d[4] = cd[i0 + 4];
  }
  float e0 = 0.f, o0 = 0.f, e1 = 0.f, o1 = 0.f;
#pragma unroll
  for (int s = 0; s < 4; ++s) {
    const float rl0 = REC_LO[2 * s], rl1 = REC_LO[2 * s + 1];
    const float rh0 = REC_HI[2 * s], rh1 = REC_HI[2 * s + 1];
    if (CA) {
      e0 = fmaf(rl0, a[3 - s], e0);
      o0 = fmaf(rl1, a[3 - s], o0);
      e1 = fmaf(rl0, a[4 - s], e1);
      o1 = fmaf(rl1, a[4 - s], o1);
    }
    if (CD) {
      e0 = fmaf(rh0, d[3 - s], e0);
      o0 = fmaf(rh1, d[3 - s], o0);
      e1 = fmaf(rh0, d[4 - s], e1);
      o1 = fmaf(rh1, d[4 - s], o1);
    }
  }
  r = make_float4(e0, o0, e1, o1);
}

template <bool CA, bool CD>
__device__ __forceinline__ void idwt_any(const float* __restrict__ ca,
                                         const float* __restrict__ cd, int n,
                                         float* __restrict__ out, int tid) {
  const int npair = (n - 3) / 2;
  float4* out4 = reinterpret_cast<float4*>(out);
  for (int t = tid; t < npair; t += NTHR) {
    float4 r;
    idwt_pair<CA, CD>(ca, cd, 2 * t, r);
    out4[t] = r;
  }
}

__global__ __launch_bounds__(NTHR, 8) void wavelet_kernel(
    const float* __restrict__ x, float* __restrict__ out_physio,
    float* __restrict__ out_identity) {
  // LDS: 10,024 floats = 40,096 B <= 40,960 B -> still 4 blocks/CU (wave cap 32/CU)
  // A: a1 -> {a3@0, d3@+632, a4@+1264, d4@+1584} -> r3@0 -> r1
  // B: d1 (live to end);  C: a2 -> r2;  D: d2;  E: s1
  __shared__ __align__(16) float A[2504];
  __shared__ __align__(16) float B[2504];
  __shared__ __align__(16) float E[2504];
  __shared__ __align__(16) float C[1256];
  __shared__ __align__(16) float D[1256];

  float* const a3 = A;            // 631 @ A[0..630]
  float* const d3 = A + 632;      // 631 @ A[632..1262]
  float* const a4 = A + 1264;     // 319
  float* const d4 = A + 1584;     // 319 (ends 1902 < 2504)

  const int b = blockIdx.x;
  const int tid = threadIdx.x;
  const float* xrow = x + (size_t)b * NROW;

  // S1: level-1 dwt straight from global (x row is L1/L2-resident)
  dwt_glob(xrow, NROW, NB1, A, B, tid);        // a1 -> A, d1 -> B
  __syncthreads();
  // S2
  dwt_step(A, NB1, NB2, C, D, tid);            // a2 -> C, d2 -> D
  __syncthreads();
  // S3
  dwt_step(C, NB2, NB3, a3, d3, tid);          // a1 dead: a3/d3 into A
  __syncthreads();
  // S4: dwt4 (160 pairs) packed with s1 = idwt(0,d2) (626 pairs) — both underused
  dwt_step(a3, NB3, NB4, a4, d4, tid);         // reads A[0..630], writes A[1264..]
  idwt_any<false, true>(nullptr, D, NB2, E, tid);  // s1 -> E (reads D from S2)
  __syncthreads();
  // S5: physio chain
  idwt_any<true, true>(a4, d4, NB4, A, tid);   // r3 -> A[0..631] (a3 dead)
  __syncthreads();
  // S6
  idwt_any<true, true>(A, d3, NB3, C, tid);    // r2 -> C (a2 dead)
  __syncthreads();
  // S7
  idwt_any<true, false>(C, nullptr, NB2, A, tid);  // r1 -> A[0..2503]
  __syncthreads();
  // S8: both final writes, no barrier between (physio reads A; identity reads E,B)
  idwt_any<true, false>(A, nullptr, NB1, out_physio + (size_t)b * NROW, tid);
  idwt_any<true, true>(E, B, NB1, out_identity + (size_t)b * NROW, tid);
}

extern "C" void kernel_launch(void* const* d_in, const int* in_sizes, int n_in,
                              void* d_out, int out_size, void* d_ws, size_t ws_size,
                              hipStream_t stream) {
  const float* x = (const float*)d_in[0];
  float* out = (float*)d_out;
  const int B = in_sizes[0] / NROW;  // 4096
  wavelet_kernel<<<dim3(B), dim3(NTHR), 0, stream>>>(x, out, out + (size_t)B * NROW);
}